// Round 7
// baseline (30.502 us; speedup 1.0000x reference)
//
#include <hip/hip_runtime.h>
#include <hip/hip_fp16.h>

// NEAT sparse MLP fwd. LAYER_SIZES=[256,512,512,512,512,64], FAN_IN=32, BATCH=2048.
// OFFSETS=[0,256,768,1280,1792,2304,2368]; E_TOT=67584.
//
// R7: single kernel, no pack. R4 gather structure (f16 acts [node][8] in LDS,
// one ds_read_b128 per edge feeds 8 batch rows) + register double-buffering of
// the edge records: all src/w addresses are STATIC, so next half-layer's
// (int4,float4) loads are issued before the current half-layer's compute,
// keeping >=8 global loads in flight at all times. offPrev folded into the LDS
// base pointer. grid=256 (1 block/CU), 512 threads (thread==node).

typedef _Float16 half8_t  __attribute__((ext_vector_type(8)));
typedef float    float8_t __attribute__((ext_vector_type(8)));

constexpr int TB    = 8;
constexpr int BLOCK = 512;

__device__ __forceinline__ float sigmoidf(float s)
{
    return __fdividef(1.0f, 1.0f + __expf(-s));
}

__global__ __launch_bounds__(BLOCK, 2) void neat_fwd(
    const float* __restrict__ x,
    const float* __restrict__ w,
    const int*   __restrict__ src,
    float*       __restrict__ out)
{
    __shared__ __align__(16) _Float16 bufA[512 * TB];   // 8 KB
    __shared__ __align__(16) _Float16 bufB[512 * TB];   // 8 KB
    __shared__ float l5p[512 * 9];                      // 18 KB, stride-9 pad

    const int tid    = threadIdx.x;
    const int batch0 = blockIdx.x * TB;

    const int4*   s4p = (const int4*)src;
    const float4* w4p = (const float4*)w;
    const int rbase = tid * 8;              // int4 index of (layer0, chunk0)

    // Prefetch layer-0 chunks 0..3 immediately (no dependencies).
    int4 sA[4]; float4 wA[4];
#pragma unroll
    for (int c = 0; c < 4; ++c) { sA[c] = s4p[rbase + c]; wA[c] = w4p[rbase + c]; }

    // Stage input layer as f16 [node][8]: 256 nodes x 8 rows.
    {
        const int r  = tid >> 6;          // 0..7
        const int c4 = (tid & 63) * 4;    // node base
        const float4 v = *(const float4*)(x + (size_t)(batch0 + r) * 256 + c4);
        bufA[(c4 + 0) * TB + r] = (_Float16)v.x;
        bufA[(c4 + 1) * TB + r] = (_Float16)v.y;
        bufA[(c4 + 2) * TB + r] = (_Float16)v.z;
        bufA[(c4 + 3) * TB + r] = (_Float16)v.w;
    }
    __syncthreads();

#define GATHER8(SS, WW)                                                          \
    do {                                                                         \
        const half8_t a0 = *(const half8_t*)(pv + ((unsigned)(SS).x << 4));      \
        const half8_t a1 = *(const half8_t*)(pv + ((unsigned)(SS).y << 4));      \
        const half8_t a2 = *(const half8_t*)(pv + ((unsigned)(SS).z << 4));      \
        const half8_t a3 = *(const half8_t*)(pv + ((unsigned)(SS).w << 4));      \
        _Pragma("unroll") for (int k = 0; k < 8; ++k) acc[k] = fmaf((float)a0[k], (WW).x, acc[k]); \
        _Pragma("unroll") for (int k = 0; k < 8; ++k) acc[k] = fmaf((float)a1[k], (WW).y, acc[k]); \
        _Pragma("unroll") for (int k = 0; k < 8; ++k) acc[k] = fmaf((float)a2[k], (WW).z, acc[k]); \
        _Pragma("unroll") for (int k = 0; k < 8; ++k) acc[k] = fmaf((float)a3[k], (WW).w, acc[k]); \
    } while (0)

    _Float16* prev = bufA;
    _Float16* cur  = bufB;

    int4 sB[4]; float4 wB[4];
    int4 s5; float4 w5;
    const int r5 = 16384 + (tid & 63) * 8 + (tid >> 6);   // layer-5 record idx

    // Layers 1..4 (512 nodes each): thread == node; half-layer reg double-buffer.
#pragma unroll
    for (int l = 0; l < 4; ++l) {
        const int offPrev = (l == 0) ? 0 : (256 + (l - 1) * 512);
        const char* pv = (const char*)prev - (offPrev << 4);   // fold offset
        const int lb = l * 4096 + rbase;

        // Issue loads for this layer's chunks 4..7 before computing 0..3.
#pragma unroll
        for (int c = 0; c < 4; ++c) { sB[c] = s4p[lb + 4 + c]; wB[c] = w4p[lb + 4 + c]; }

        float8_t acc = {0.f, 0.f, 0.f, 0.f, 0.f, 0.f, 0.f, 0.f};
#pragma unroll
        for (int c = 0; c < 4; ++c) GATHER8(sA[c], wA[c]);

        // Issue loads for the NEXT layer's chunks 0..3 (or layer-5 record).
        if (l < 3) {
#pragma unroll
            for (int c = 0; c < 4; ++c) { sA[c] = s4p[lb + 4096 + c]; wA[c] = w4p[lb + 4096 + c]; }
        } else {
            s5 = s4p[r5]; w5 = w4p[r5];
        }

#pragma unroll
        for (int c = 0; c < 4; ++c) GATHER8(sB[c], wB[c]);

        half8_t r;
#pragma unroll
        for (int k = 0; k < 8; ++k)
            r[k] = (_Float16)sigmoidf(acc[k]);
        *(half8_t*)(cur + tid * TB) = r;
        __syncthreads();
        _Float16* t = prev; prev = cur; cur = t;
    }

    // Layer 5: 64 nodes x 32 edges; thread tid = c*64+n handles 4 edges of
    // node n (chunk c). Partial float8 -> padded LDS, then reduce.
    {
        const char* pv = (const char*)prev - (1792 << 4);
        float8_t acc = {0.f, 0.f, 0.f, 0.f, 0.f, 0.f, 0.f, 0.f};
        GATHER8(s5, w5);
        float* dst = l5p + tid * 9;
#pragma unroll
        for (int k = 0; k < 8; ++k)
            dst[k] = acc[k];
    }
    __syncthreads();

    // Reduce 8 chunk-partials per (node, batch row) and store.
    {
        const int n = tid & 63;
        const int b = tid >> 6;
        float s = 0.f;
#pragma unroll
        for (int c = 0; c < 8; ++c)
            s += l5p[(c * 64 + n) * 9 + b];
        out[(size_t)(batch0 + b) * 64 + n] = sigmoidf(s);
    }
#undef GATHER8
}

extern "C" void kernel_launch(void* const* d_in, const int* in_sizes, int n_in,
                              void* d_out, int out_size, void* d_ws, size_t ws_size,
                              hipStream_t stream)
{
    const float* x   = (const float*)d_in[0];
    const float* w   = (const float*)d_in[1];
    const int*   src = (const int*)d_in[2];
    float* out = (float*)d_out;

    const int batch = in_sizes[0] / 256;   // 2048
    const int grid  = batch / TB;          // 256

    neat_fwd<<<grid, BLOCK, 0, stream>>>(x, w, src, out);
}

// Round 8
// 20.976 us; speedup vs baseline: 1.4542x; 1.4542x over previous
//
#include <hip/hip_runtime.h>
#include <hip/hip_fp16.h>

// NEAT sparse MLP fwd. LAYER_SIZES=[256,512,512,512,512,64], FAN_IN=32, BATCH=2048.
// OFFSETS=[0,256,768,1280,1792,2304,2368]; E_TOT=67584.
//
// R8 = R6/R4 fwd structure + (1) cross-barrier register prefetch of next layer's
// packed records (compiler can't hoist loads across s_barrier), (2) simple
// arithmetic-only pack (identity layout for layer 5), (3) layer-5 reduced via
// __shfl_xor within 8-lane groups (no LDS scratch, one less barrier).
// Acts f16 [node][8] in LDS; one ds_read_b128 per edge feeds 8 batch rows.
// Packed 4 B record = (local_src*16) | (w_f16 << 16), chunk-transposed per
// 64-node group so wave record loads are coalesced. grid=256, 512 thr.

typedef _Float16 half8_t  __attribute__((ext_vector_type(8)));
typedef float    float8_t __attribute__((ext_vector_type(8)));

constexpr int TB    = 8;
constexpr int BLOCK = 512;
constexpr int E_TOT = 67584;

__global__ __launch_bounds__(256) void pack_edges(const int* __restrict__ src,
                                                  const float* __restrict__ w,
                                                  unsigned* __restrict__ rec)
{
    const int o = blockIdx.x * 256 + threadIdx.x;
    if (o >= E_TOT) return;
    int eid, offPrev;
    if (o < 65536) {
        // 512-wide layers: word idx ol = (((g*8 + c)*64 + i)*4 + q)
        // covers eid = e0 + (g*64+i)*32 + c*4 + q.
        const int layer = o >> 14;
        const int e0    = layer << 14;
        offPrev = (layer == 0) ? 0 : (256 + (layer - 1) * 512);
        const int ol = o - e0;
        const int q = ol & 3, t = ol >> 2;
        const int i = t & 63, c = (t >> 6) & 7, g = t >> 9;
        eid = e0 + (g * 64 + i) * 32 + c * 4 + q;
    } else {
        // layer 5: identity (raw order is already (n*8+c) record-major).
        offPrev = 1792;
        eid = o;
    }
    const unsigned off = (unsigned)(src[eid] - offPrev) * 16u;  // byte off, [node][8] f16
    const unsigned hw  = (unsigned)__half_as_ushort(__float2half(w[eid]));
    rec[o] = off | (hw << 16);
}

__device__ __forceinline__ float sigmoidf(float s)
{
    return __fdividef(1.0f, 1.0f + __expf(-s));
}

template<bool PACKED>
__global__ __launch_bounds__(BLOCK) void neat_fwd(
    const float* __restrict__ x,
    const float* __restrict__ w,
    const int*   __restrict__ src,
    const int4*  __restrict__ rp,      // packed records as int4 (4 edges)
    float*       __restrict__ out)
{
    __shared__ __align__(16) _Float16 bufA[512 * TB];   // 8 KB
    __shared__ __align__(16) _Float16 bufB[512 * TB];   // 8 KB

    const int tid    = threadIdx.x;
    const int batch0 = blockIdx.x * TB;
    const int base   = (tid >> 6) * 512 + (tid & 63);   // int4 idx in a 512-layer

    int4 rcur[8], rnxt[8];
    if (PACKED) {
        // Prefetch layer-1 records while input staging runs.
#pragma unroll
        for (int c = 0; c < 8; ++c) rcur[c] = rp[base + c * 64];
    }

    // Stage input layer as f16 [node][8]: 256 nodes x 8 rows.
    {
        const int r  = tid >> 6;          // 0..7
        const int c4 = (tid & 63) * 4;    // node base
        const float4 v = *(const float4*)(x + (size_t)(batch0 + r) * 256 + c4);
        bufA[(c4 + 0) * TB + r] = (_Float16)v.x;
        bufA[(c4 + 1) * TB + r] = (_Float16)v.y;
        bufA[(c4 + 2) * TB + r] = (_Float16)v.z;
        bufA[(c4 + 3) * TB + r] = (_Float16)v.w;
    }
    __syncthreads();

    _Float16* prev = bufA;
    _Float16* cur  = bufB;

#define EDGE(RR, ACC)                                                          \
    do {                                                                       \
        const unsigned rr = (unsigned)(RR);                                    \
        const float wf = __half2float(__ushort_as_half((unsigned short)(rr >> 16))); \
        const half8_t a = *(const half8_t*)(pv + (rr & 0xffffu));              \
        _Pragma("unroll")                                                      \
        for (int k = 0; k < 8; ++k)                                            \
            ACC[k] = fmaf((float)a[k], wf, ACC[k]);                            \
    } while (0)

#define EDGE_RAW(SRCID, WF, ACC)                                               \
    do {                                                                       \
        const float wf = (WF);                                                 \
        const half8_t a = *(const half8_t*)(pv + (unsigned)((SRCID) - offPrev) * 16u); \
        _Pragma("unroll")                                                      \
        for (int k = 0; k < 8; ++k)                                            \
            ACC[k] = fmaf((float)a[k], wf, ACC[k]);                            \
    } while (0)

    // Layers 1..4 (512 nodes each): thread == node.
#pragma unroll
    for (int l = 0; l < 4; ++l) {
        // Issue next layer's record loads FIRST: they fly during this layer's
        // gather+FMA work and across the barrier the compiler can't cross.
        if (PACKED) {
            if (l < 3) {
                const int4* rn = rp + (l + 1) * 4096;
#pragma unroll
                for (int c = 0; c < 8; ++c) rnxt[c] = rn[base + c * 64];
            } else {
                rnxt[0] = rp[16384 + tid];   // layer-5 record (identity layout)
            }
        }

        const char* pv = (const char*)prev;
        float8_t acc = {0.f, 0.f, 0.f, 0.f, 0.f, 0.f, 0.f, 0.f};
        if (PACKED) {
#pragma unroll
            for (int c = 0; c < 8; ++c) {
                const int4 r4 = rcur[c];
                EDGE(r4.x, acc);
                EDGE(r4.y, acc);
                EDGE(r4.z, acc);
                EDGE(r4.w, acc);
            }
        } else {
            const int e0 = l * 16384;
            const int offPrev = (l == 0) ? 0 : (256 + (l - 1) * 512);
            const int ebase = e0 + tid * 32;
#pragma unroll
            for (int c = 0; c < 8; ++c) {
                const int4   s4 = *(const int4*)(src + ebase + c * 4);
                const float4 w4 = *(const float4*)(w + ebase + c * 4);
                EDGE_RAW(s4.x, w4.x, acc);
                EDGE_RAW(s4.y, w4.y, acc);
                EDGE_RAW(s4.z, w4.z, acc);
                EDGE_RAW(s4.w, w4.w, acc);
            }
        }

        half8_t r;
#pragma unroll
        for (int k = 0; k < 8; ++k)
            r[k] = (_Float16)sigmoidf(acc[k]);
        *(half8_t*)(cur + tid * TB) = r;
        __syncthreads();
        _Float16* t = prev; prev = cur; cur = t;

        if (PACKED) {
#pragma unroll
            for (int c = 0; c < 8; ++c) rcur[c] = rnxt[c];
        }
    }

    // Layer 5: 64 nodes x 32 edges. Thread tid: n = tid>>3, c = tid&7 handles
    // 4 edges; the 8 partials of a node live in 8 consecutive lanes ->
    // __shfl_xor reduce, no LDS, no extra barrier.
    {
        const char* pv = (const char*)prev;
        float8_t acc = {0.f, 0.f, 0.f, 0.f, 0.f, 0.f, 0.f, 0.f};
        if (PACKED) {
            const int4 r4 = rcur[0];
            EDGE(r4.x, acc);
            EDGE(r4.y, acc);
            EDGE(r4.z, acc);
            EDGE(r4.w, acc);
        } else {
            const int offPrev = 1792;
            const int eb = 65536 + tid * 4;
            const int4   s4 = *(const int4*)(src + eb);
            const float4 w4 = *(const float4*)(w + eb);
            EDGE_RAW(s4.x, w4.x, acc);
            EDGE_RAW(s4.y, w4.y, acc);
            EDGE_RAW(s4.z, w4.z, acc);
            EDGE_RAW(s4.w, w4.w, acc);
        }
#pragma unroll
        for (int m = 1; m <= 4; m <<= 1) {
#pragma unroll
            for (int k = 0; k < 8; ++k)
                acc[k] += __shfl_xor(acc[k], m, 64);
        }
        if ((tid & 7) == 0) {
            const int n = tid >> 3;
#pragma unroll
            for (int b = 0; b < 8; ++b)
                out[(size_t)(batch0 + b) * 64 + n] = sigmoidf(acc[b]);
        }
    }
#undef EDGE
#undef EDGE_RAW
}

extern "C" void kernel_launch(void* const* d_in, const int* in_sizes, int n_in,
                              void* d_out, int out_size, void* d_ws, size_t ws_size,
                              hipStream_t stream)
{
    const float* x   = (const float*)d_in[0];
    const float* w   = (const float*)d_in[1];
    const int*   src = (const int*)d_in[2];
    float* out = (float*)d_out;

    const int batch = in_sizes[0] / 256;   // 2048
    const int grid  = batch / TB;          // 256

    unsigned* rec = (unsigned*)d_ws;

    if (ws_size >= (size_t)E_TOT * 4) {
        pack_edges<<<(E_TOT + 255) / 256, 256, 0, stream>>>(src, w, rec);
        neat_fwd<true><<<grid, BLOCK, 0, stream>>>(x, w, src, (const int4*)rec, out);
    } else {
        neat_fwd<false><<<grid, BLOCK, 0, stream>>>(x, w, src, (const int4*)rec, out);
    }
}